// Round 1
// baseline (16764.041 us; speedup 1.0000x reference)
//
#include <hip/hip_runtime.h>
#include <cstdint>
#include <cstddef>
#include <math.h>

#define TPB 256

// ---------------- direct convolution ----------------
// one thread per output pixel; weights for (co) staged in LDS.
// grid: (ceil(Ho*Wo/TPB), Co, N)
template <int K, int S>
__global__ void conv_direct(const float* __restrict__ in, const float* __restrict__ wt,
                            const float* __restrict__ bias, float* __restrict__ out,
                            int Ci, int Hi, int Wi, int Co, int Ho, int Wo) {
  extern __shared__ float wsh[];
  const int co = blockIdx.y;
  const int n  = blockIdx.z;
  const int nw = Ci * K * K;
  for (int i = threadIdx.x; i < nw; i += blockDim.x)
    wsh[i] = wt[(size_t)co * nw + i];
  __syncthreads();
  const int total = Ho * Wo;
  const int p = blockIdx.x * blockDim.x + threadIdx.x;
  if (p >= total) return;
  const int oy = p / Wo, ox = p - oy * Wo;
  const float* inp = in + ((size_t)n * Ci) * (size_t)(Hi * Wi)
                        + (size_t)(oy * S) * Wi + (ox * S);
  float acc = bias[co];
  for (int ci = 0; ci < Ci; ++ci) {
    const float* ip = inp + (size_t)ci * (Hi * Wi);
    const float* wp = wsh + ci * K * K;
#pragma unroll
    for (int ky = 0; ky < K; ++ky) {
      const float* r = ip + ky * Wi;
#pragma unroll
      for (int kx = 0; kx < K; ++kx)
        acc = fmaf(r[kx], wp[ky * K + kx], acc);
    }
  }
  out[((size_t)n * Co + co) * (size_t)total + p] = acc;
}

// ---------------- BN statistics (training mode) ----------------
// one block per channel; deterministic tree reduction.
__global__ void bn_stats(const float* __restrict__ x, float* __restrict__ stats,
                         int N, int C, int HW) {
  const int c = blockIdx.x;
  float s = 0.f, q = 0.f;
  for (int n = 0; n < N; ++n) {
    const float* p = x + ((size_t)n * C + c) * (size_t)HW;
    for (int i = threadIdx.x; i < HW; i += blockDim.x) {
      float v = p[i];
      s += v;
      q = fmaf(v, v, q);
    }
  }
#pragma unroll
  for (int off = 32; off > 0; off >>= 1) {
    s += __shfl_down(s, off, 64);
    q += __shfl_down(q, off, 64);
  }
  __shared__ float shs[8], shq[8];
  const int lane = threadIdx.x & 63, wid = threadIdx.x >> 6;
  if (lane == 0) { shs[wid] = s; shq[wid] = q; }
  __syncthreads();
  if (threadIdx.x == 0) {
    float ts = 0.f, tq = 0.f;
    const int nw = blockDim.x >> 6;
    for (int w = 0; w < nw; ++w) { ts += shs[w]; tq += shq[w]; }
    const float cnt = (float)N * (float)HW;
    const float mean = ts / cnt;
    const float var = tq / cnt - mean * mean;
    stats[2 * c] = mean;
    stats[2 * c + 1] = rsqrtf(var + 1e-5f);
  }
}

// ---------------- BN normalize (+optional ReLU), in place ----------------
__global__ void bn_apply(float* __restrict__ x, const float* __restrict__ stats,
                         const float* __restrict__ g, const float* __restrict__ b,
                         int C, int HW, long total, int relu) {
  long i = (long)blockIdx.x * blockDim.x + threadIdx.x;
  if (i >= total) return;
  const int c = (int)((i / HW) % C);
  float v = (x[i] - stats[2 * c]) * stats[2 * c + 1] * g[c] + b[c];
  if (relu) v = fmaxf(v, 0.f);
  x[i] = v;
}

// ---------------- MaxPool 3x3 stride 2, VALID ----------------
__global__ void maxpool3s2(const float* __restrict__ in, float* __restrict__ out,
                           int Hi, int Wi, int Ho, int Wo, long total) {
  long idx = (long)blockIdx.x * blockDim.x + threadIdx.x;
  if (idx >= total) return;
  const int hw = Ho * Wo;
  const int p = (int)(idx % hw);
  const long plane = idx / hw;
  const int oy = p / Wo, ox = p - oy * Wo;
  const float* base = in + plane * (size_t)(Hi * Wi) + (size_t)(2 * oy) * Wi + 2 * ox;
  float m = -INFINITY;
#pragma unroll
  for (int dy = 0; dy < 3; ++dy)
#pragma unroll
    for (int dx = 0; dx < 3; ++dx)
      m = fmaxf(m, base[dy * Wi + dx]);
  out[idx] = m;
}

// ---------------- cross-correlation over B*C channels ----------------
// one block per output pixel (17*17 = 289 blocks)
__global__ void xcorr(const float* __restrict__ o1, const float* __restrict__ o2,
                      float* __restrict__ corr, int BC, int H1, int W1,
                      int H2, int W2, int Wo, float scale) {
  const int p = blockIdx.x;
  const int oy = p / Wo, ox = p - oy * Wo;
  const int per = H2 * W2;
  const long total = (long)BC * per;
  float acc = 0.f;
  for (long i = threadIdx.x; i < total; i += blockDim.x) {
    const int bc = (int)(i / per);
    const int q = (int)(i - (long)bc * per);
    const int ky = q / W2, kx = q - ky * W2;
    acc = fmaf(o1[((size_t)bc * H1 + oy + ky) * W1 + ox + kx], o2[i], acc);
  }
#pragma unroll
  for (int off = 32; off > 0; off >>= 1) acc += __shfl_down(acc, off, 64);
  __shared__ float sh[8];
  const int lane = threadIdx.x & 63, wid = threadIdx.x >> 6;
  if (lane == 0) sh[wid] = acc;
  __syncthreads();
  if (threadIdx.x == 0) {
    float t = 0.f;
    const int nw = blockDim.x >> 6;
    for (int w = 0; w < nw; ++w) t += sh[w];
    corr[p] = t * scale;
  }
}

__global__ void bcast_out(const float* __restrict__ corr, float* __restrict__ out,
                          int P, int total) {
  int i = blockIdx.x * blockDim.x + threadIdx.x;
  if (i < total) out[i] = corr[i % P];
}

// ---------------- host-side orchestration ----------------
static void launch_conv(const float* in, const float* w, const float* b, float* out,
                        int N, int Ci, int Hi, int Wi, int Co, int K, int S,
                        int Ho, int Wo, hipStream_t stream) {
  dim3 grid((unsigned)((Ho * Wo + TPB - 1) / TPB), (unsigned)Co, (unsigned)N);
  size_t shm = (size_t)Ci * K * K * sizeof(float);
  if (K == 11)
    conv_direct<11, 2><<<grid, TPB, shm, stream>>>(in, w, b, out, Ci, Hi, Wi, Co, Ho, Wo);
  else if (K == 5)
    conv_direct<5, 1><<<grid, TPB, shm, stream>>>(in, w, b, out, Ci, Hi, Wi, Co, Ho, Wo);
  else
    conv_direct<3, 1><<<grid, TPB, shm, stream>>>(in, w, b, out, Ci, Hi, Wi, Co, Ho, Wo);
}

static void backbone(const float* x, int Hin, int Win, int N,
                     const float* const cw[5], const float* const cb[5],
                     const float* const bg[5], const float* const bb[5],
                     float* bufA, float* bufB, float* obuf, float* stats,
                     hipStream_t stream) {
  static const int Ci[5] = {3, 96, 256, 192, 192};
  static const int Co[5] = {96, 256, 192, 192, 128};
  static const int K[5]  = {11, 5, 3, 3, 3};
  static const int S[5]  = {2, 1, 1, 1, 1};
  float* bufs[2] = {bufA, bufB};
  const float* cur = x;
  int curb = -1;  // which buffer holds cur (-1 = external input)
  int H = Hin, W = Win;
  for (int L = 0; L < 5; ++L) {
    const int Ho = (H - K[L]) / S[L] + 1;
    const int Wo = (W - K[L]) / S[L] + 1;
    const int dstb = (curb == 0) ? 1 : 0;
    float* cout = (L == 4) ? obuf : bufs[dstb];
    launch_conv(cur, cw[L], cb[L], cout, N, Ci[L], H, W, Co[L], K[L], S[L], Ho, Wo, stream);
    const int hw = Ho * Wo;
    bn_stats<<<Co[L], TPB, 0, stream>>>(cout, stats, N, Co[L], hw);
    const long tot = (long)N * Co[L] * hw;
    bn_apply<<<(unsigned)((tot + TPB - 1) / TPB), TPB, 0, stream>>>(
        cout, stats, bg[L], bb[L], Co[L], hw, tot, (L < 4) ? 1 : 0);
    if (L < 2) {
      const int Hp = (Ho - 3) / 2 + 1, Wp = (Wo - 3) / 2 + 1;
      const long ptot = (long)N * Co[L] * Hp * Wp;
      float* pdst = bufs[1 - dstb];
      maxpool3s2<<<(unsigned)((ptot + TPB - 1) / TPB), TPB, 0, stream>>>(
          cout, pdst, Ho, Wo, Hp, Wp, ptot);
      cur = pdst;
      curb = 1 - dstb;
      H = Hp; W = Wp;
    } else {
      cur = cout;
      curb = dstb;
      H = Ho; W = Wo;
    }
  }
}

extern "C" void kernel_launch(void* const* d_in, const int* in_sizes, int n_in,
                              void* d_out, int out_size, void* d_ws, size_t ws_size,
                              hipStream_t stream) {
  (void)in_sizes; (void)n_in; (void)ws_size;
  const float* input1 = (const float*)d_in[0];
  const float* input2 = (const float*)d_in[1];
  const float* cw[5], *cb[5], *bg[5], *bb[5];
  for (int i = 0; i < 5; ++i) {
    cw[i] = (const float*)d_in[2 + 2 * i];
    cb[i] = (const float*)d_in[3 + 2 * i];
    bg[i] = (const float*)d_in[12 + 2 * i];
    bb[i] = (const float*)d_in[13 + 2 * i];
  }
  float* ws = (float*)d_ws;
  // workspace layout (floats)
  const size_t Asz = 46476288;   // conv1 raw (branch1): 32*96*123*123
  const size_t Bsz = 11430912;   // pool1 out (branch1): 32*96*61*61
  float* A  = ws;
  float* Bb_ = A + Asz;
  float* O1 = Bb_ + Bsz;                // 32*128*22*22 = 1982464
  float* O2 = O1 + 1982464;             // 32*128*6*6   = 147456
  float* stats = O2 + 147456;           // 2*256
  float* corr  = stats + 512;           // 289

  backbone(input1, 255, 255, 32, cw, cb, bg, bb, A, Bb_, O1, stats, stream);
  backbone(input2, 127, 127, 32, cw, cb, bg, bb, A, Bb_, O2, stats, stream);

  xcorr<<<289, TPB, 0, stream>>>(O1, O2, corr, 32 * 128, 22, 22, 6, 6, 17,
                                 1.0f / 147456.0f);
  bcast_out<<<(9248 + TPB - 1) / TPB, TPB, 0, stream>>>(corr, (float*)d_out, 289, 9248);
}

// Round 3
// 3701.005 us; speedup vs baseline: 4.5296x; 4.5296x over previous
//
#include <hip/hip_runtime.h>
#include <hip/hip_bf16.h>
#include <cstdint>
#include <cstddef>

typedef __attribute__((ext_vector_type(8))) _Float16 f16x8;
typedef __attribute__((ext_vector_type(4))) float f32x4;

__device__ __forceinline__ float h2f(unsigned short u) {
  union { unsigned short s; _Float16 h; } x; x.s = u; return (float)x.h;
}
__device__ __forceinline__ unsigned short f2h(float f) {
  union { unsigned short s; _Float16 h; } x; x.h = (_Float16)f; return x.s;
}
__device__ __forceinline__ void gload_lds16(const void* g, void* l) {
  __builtin_amdgcn_global_load_lds((const __attribute__((address_space(1))) unsigned int*)g,
                                   (__attribute__((address_space(3))) unsigned int*)l, 16, 0, 0);
}

// ============ conv1: Ci=3, K=11, S=2, Co=96; fp32 in NCHW -> fp16 out NHWC ============
// block: 256 thr = 32 co x 8 subs (8 px each) -> 64 px x 32 co per block
__global__ __launch_bounds__(256)
void conv1_k(const float* __restrict__ in, const float* __restrict__ wt,
             unsigned short* __restrict__ out, int Hi, int Wi, int Ho, int Wo) {
  __shared__ float sIn[3][11][140];
  __shared__ float sW[11][32][12];
  const int t = threadIdx.x;
  const int oy = blockIdx.y;
  const int n = blockIdx.z / 3;
  const int co0 = (blockIdx.z % 3) * 32;
  const int px0 = blockIdx.x * 64;
  const int x0 = px0 * 2;
  for (int e = t; e < 3 * 11 * 140; e += 256) {
    int ci = e / (11 * 140);
    int r = e - ci * 11 * 140;
    int ky = r / 140;
    int j = r - ky * 140;
    int x = x0 + j;
    float v = 0.f;
    if (x < Wi) v = in[((long)(n * 3 + ci) * Hi + (2 * oy + ky)) * Wi + x];
    sIn[ci][ky][j] = v;
  }
  const int co_r = t & 31;
  const int sub = t >> 5;
  float acc[8];
#pragma unroll
  for (int p = 0; p < 8; ++p) acc[p] = 0.f;
  for (int ci = 0; ci < 3; ++ci) {
    __syncthreads();
    for (int e = t; e < 11 * 32 * 12; e += 256) {
      int ky = e / 384;
      int r = e - ky * 384;
      int cr = r / 12;
      int j = r - cr * 12;
      float v = 0.f;
      if (j < 11) v = wt[(co0 + cr) * 363 + ci * 121 + ky * 11 + j];
      sW[ky][cr][j] = v;
    }
    __syncthreads();
#pragma unroll 1
    for (int ky = 0; ky < 11; ++ky) {
      float4 rr[7];
      const float4* ip = (const float4*)&sIn[ci][ky][sub * 16];
#pragma unroll
      for (int i2 = 0; i2 < 7; ++i2) rr[i2] = ip[i2];
      const float4* wp = (const float4*)&sW[ky][co_r][0];
      float4 w0 = wp[0], w1 = wp[1], w2 = wp[2];
      float win[28];
#pragma unroll
      for (int i2 = 0; i2 < 7; ++i2) {
        win[4 * i2] = rr[i2].x; win[4 * i2 + 1] = rr[i2].y;
        win[4 * i2 + 2] = rr[i2].z; win[4 * i2 + 3] = rr[i2].w;
      }
      const float wv[12] = {w0.x, w0.y, w0.z, w0.w, w1.x, w1.y, w1.z, w1.w,
                            w2.x, w2.y, w2.z, w2.w};
#pragma unroll
      for (int kx = 0; kx < 11; ++kx) {
        float wk = wv[kx];
#pragma unroll
        for (int p = 0; p < 8; ++p)
          acc[p] = fmaf(win[2 * p + kx], wk, acc[p]);
      }
    }
  }
  const int pxb = px0 + sub * 8;
#pragma unroll
  for (int p = 0; p < 8; ++p) {
    int px = pxb + p;
    if (px < Wo)
      out[((long)(n * Ho + oy) * Wo + px) * 96 + co0 + co_r] = f2h(acc[p]);
  }
}

// ============ implicit-GEMM MFMA conv (stride 1, VALID), fp16 ============
// in: f16 NHWC [N,Hi,Wi,Ci]; wt: f16 [K][K][Co_pad][Ci]; out: f16 NHWC [N,Ho,Wo,Co_real]
// block tile: 128 px x 128 co, BK=32; 4 waves, each 64px x 64co (4x4 16x16 frags)
template <int K>
__global__ __launch_bounds__(256)
void conv_mfma(const unsigned short* __restrict__ in, const unsigned short* __restrict__ wt,
               unsigned short* __restrict__ out,
               int Ci, int Hi, int Wi, int Ho, int Wo, int Co_pad, int Co_real, int NPIX) {
  __shared__ __align__(16) unsigned short sA[128 * 32];
  __shared__ __align__(16) unsigned short sB[128 * 32];
  __shared__ int sOB[128];
  const int t = threadIdx.x;
  const int px0 = blockIdx.x * 128;
  const int co0 = blockIdx.y * 128;
  if (t < 128) {
    int g = px0 + t;
    int ob = -1;
    if (g < NPIX) {
      int n = g / (Ho * Wo);
      int r = g - n * Ho * Wo;
      int oy = r / Wo, ox = r - (r / Wo) * Wo;
      ob = ((n * Ho + oy) * Wo + ox) * Co_real;
    }
    sOB[t] = ob;
  }
  long rbase[2];
#pragma unroll
  for (int i = 0; i < 2; ++i) {
    int pxl = i * 64 + (t >> 2);
    int g = px0 + pxl;
    long rb = 0;
    if (g < NPIX) {
      int n = g / (Ho * Wo);
      int r = g - n * Ho * Wo;
      int oy = r / Wo, ox = r - (r / Wo) * Wo;
      rb = ((long)(n * Hi + oy) * Wi + ox) * Ci;
    }
    rbase[i] = rb;
  }
  const int seg8 = (t & 3) * 8;
  const int colA = t >> 2;
  f32x4 acc[4][4];
  f32x4 zz = {0.f, 0.f, 0.f, 0.f};
#pragma unroll
  for (int m = 0; m < 4; ++m)
#pragma unroll
    for (int n = 0; n < 4; ++n) acc[m][n] = zz;
  const int w = t >> 6;
  const int l = t & 63;
  const int wpx = (w & 1) * 64, wco = (w >> 1) * 64;
  const int arow = wpx + (l & 15);
  const int brow = wco + (l & 15);
  const int q8 = (l >> 4) * 8;
  int ci0 = 0, kx = 0, ky = 0;
  const int NK = (Ci >> 5) * K * K;
  for (int kk = 0; kk < NK; ++kk) {
    long koff = (long)(ky * Wi + kx) * Ci + ci0 + seg8;
#pragma unroll
    for (int i = 0; i < 2; ++i)
      gload_lds16(in + rbase[i] + koff, &sA[(i * 256 + t) * 8]);
    long wbase = (long)((ky * K + kx) * Co_pad + co0) * Ci + ci0 + seg8;
#pragma unroll
    for (int i = 0; i < 2; ++i)
      gload_lds16(wt + wbase + (long)(i * 64 + colA) * Ci, &sB[(i * 256 + t) * 8]);
    __syncthreads();
    f16x8 av[4], bv[4];
#pragma unroll
    for (int m = 0; m < 4; ++m) av[m] = *(const f16x8*)&sA[(arow + m * 16) * 32 + q8];
#pragma unroll
    for (int n = 0; n < 4; ++n) bv[n] = *(const f16x8*)&sB[(brow + n * 16) * 32 + q8];
#pragma unroll
    for (int m = 0; m < 4; ++m)
#pragma unroll
      for (int n = 0; n < 4; ++n)
        acc[m][n] = __builtin_amdgcn_mfma_f32_16x16x32_f16(av[m], bv[n], acc[m][n], 0, 0, 0);
    __syncthreads();
    ci0 += 32;
    if (ci0 == Ci) { ci0 = 0; ++kx; if (kx == K) { kx = 0; ++ky; } }
  }
#pragma unroll
  for (int m = 0; m < 4; ++m) {
#pragma unroll
    for (int r = 0; r < 4; ++r) {
      int pxl = wpx + m * 16 + (l >> 4) * 4 + r;
      int ob = sOB[pxl];
#pragma unroll
      for (int n = 0; n < 4; ++n) {
        int co = co0 + wco + n * 16 + (l & 15);
        if (ob >= 0 && co < Co_real) out[ob + co] = f2h(acc[m][n][r]);
      }
    }
  }
}

// ============ weight transform: [Co][Ci][K][K] fp32 -> [K*K][Co_pad][Ci] fp16 ============
__global__ void wt_transform(const float* __restrict__ w, unsigned short* __restrict__ o,
                             int Co, int Co_pad, int Ci, int KK, long total) {
  long i = (long)blockIdx.x * blockDim.x + threadIdx.x;
  if (i >= total) return;
  int ci = (int)(i % Ci);
  long r = i / Ci;
  int co = (int)(r % Co_pad);
  int rk = (int)(r / Co_pad);
  float v = 0.f;
  if (co < Co) v = w[((long)co * Ci + ci) * KK + rk];
  o[i] = f2h(v);
}

// ============ BN stats (two-stage, deterministic) ============
__global__ void bn_stats_part(const unsigned short* __restrict__ x, float* __restrict__ part,
                              int C, long NP) {
  int c = threadIdx.x;
  if (c >= C) return;
  long per = (NP + gridDim.x - 1) / gridDim.x;
  long p0 = (long)blockIdx.x * per;
  long p1 = p0 + per;
  if (p1 > NP) p1 = NP;
  float s = 0.f, q = 0.f;
  for (long pp = p0; pp < p1; ++pp) {
    float v = h2f(x[pp * C + c]);
    s += v;
    q = fmaf(v, v, q);
  }
  part[((long)blockIdx.x * C + c) * 2] = s;
  part[((long)blockIdx.x * C + c) * 2 + 1] = q;
}

__global__ void bn_finalize(const float* __restrict__ part, const float* __restrict__ g,
                            const float* __restrict__ b, float* __restrict__ sc,
                            float* __restrict__ sh, int C, int nch, float cnt) {
  int c = threadIdx.x;
  if (c >= C) return;
  float s = 0.f, q = 0.f;
  for (int k = 0; k < nch; ++k) {
    s += part[((long)k * C + c) * 2];
    q += part[((long)k * C + c) * 2 + 1];
  }
  float m = s / cnt;
  float v = q / cnt - m * m;
  float r = rsqrtf(v + 1e-5f);
  float scl = r * g[c];
  sc[c] = scl;
  sh[c] = b[c] - m * scl;
}

// ============ BN apply (8-wide, in place or fp16->fp32) ============
template <bool RELU, bool OUTF32>
__global__ void bn_apply_k(const unsigned short* __restrict__ x, void* __restrict__ y,
                           const float* __restrict__ sc, const float* __restrict__ sh,
                           int C, long total8) {
  long i = (long)blockIdx.x * blockDim.x + threadIdx.x;
  if (i >= total8) return;
  const uint4 v = ((const uint4*)x)[i];
  long base = i * 8;
  int c0 = (int)(base % C);
  const float4 s0 = *(const float4*)&sc[c0];
  const float4 s1 = *(const float4*)&sc[c0 + 4];
  const float4 h0 = *(const float4*)&sh[c0];
  const float4 h1 = *(const float4*)&sh[c0 + 4];
  float f[8];
  f[0] = h2f((unsigned short)(v.x & 0xffff)); f[1] = h2f((unsigned short)(v.x >> 16));
  f[2] = h2f((unsigned short)(v.y & 0xffff)); f[3] = h2f((unsigned short)(v.y >> 16));
  f[4] = h2f((unsigned short)(v.z & 0xffff)); f[5] = h2f((unsigned short)(v.z >> 16));
  f[6] = h2f((unsigned short)(v.w & 0xffff)); f[7] = h2f((unsigned short)(v.w >> 16));
  const float S[8] = {s0.x, s0.y, s0.z, s0.w, s1.x, s1.y, s1.z, s1.w};
  const float H[8] = {h0.x, h0.y, h0.z, h0.w, h1.x, h1.y, h1.z, h1.w};
#pragma unroll
  for (int j = 0; j < 8; ++j) {
    f[j] = fmaf(f[j], S[j], H[j]);
    if (RELU) f[j] = fmaxf(f[j], 0.f);
  }
  if (OUTF32) {
    float4 o0 = {f[0], f[1], f[2], f[3]}, o1 = {f[4], f[5], f[6], f[7]};
    ((float4*)y)[2 * i] = o0;
    ((float4*)y)[2 * i + 1] = o1;
  } else {
    uint4 o;
    o.x = (unsigned)f2h(f[0]) | ((unsigned)f2h(f[1]) << 16);
    o.y = (unsigned)f2h(f[2]) | ((unsigned)f2h(f[3]) << 16);
    o.z = (unsigned)f2h(f[4]) | ((unsigned)f2h(f[5]) << 16);
    o.w = (unsigned)f2h(f[6]) | ((unsigned)f2h(f[7]) << 16);
    ((uint4*)y)[i] = o;
  }
}

// ============ MaxPool 3x3 s2 (NHWC fp16) ============
__global__ void pool_k(const unsigned short* __restrict__ in, unsigned short* __restrict__ out,
                       int C, int Hi, int Wi, int Ho, int Wo, long total) {
  long i = (long)blockIdx.x * blockDim.x + threadIdx.x;
  if (i >= total) return;
  int c = (int)(i % C);
  long r = i / C;
  int ox = (int)(r % Wo);
  r /= Wo;
  int oy = (int)(r % Ho);
  int n = (int)(r / Ho);
  const unsigned short* bp = in + ((long)(n * Hi + 2 * oy) * Wi + 2 * ox) * C + c;
  float m = -3.4e38f;
#pragma unroll
  for (int dy = 0; dy < 3; ++dy)
#pragma unroll
    for (int dx = 0; dx < 3; ++dx)
      m = fmaxf(m, h2f(bp[((long)dy * Wi + dx) * C]));
  out[i] = f2h(m);
}

// ============ cross-correlation (fp32, NHWC) ============
__global__ void xcorr_k(const float* __restrict__ o1, const float* __restrict__ o2,
                        float* __restrict__ corr) {
  const int p = blockIdx.x;
  const int oy = p / 17, ox = p - (p / 17) * 17;
  float acc = 0.f;
  for (int i = threadIdx.x; i < 147456; i += 256) {
    int c = i & 127;
    int r = i >> 7;
    int kx = r % 6;
    r /= 6;
    int ky = r % 6;
    int b = r / 6;
    acc = fmaf(o1[(((b * 22 + oy + ky) * 22) + ox + kx) * 128 + c], o2[i], acc);
  }
#pragma unroll
  for (int off = 32; off > 0; off >>= 1) acc += __shfl_down(acc, off, 64);
  __shared__ float sh[4];
  const int lane = threadIdx.x & 63, wid = threadIdx.x >> 6;
  if (lane == 0) sh[wid] = acc;
  __syncthreads();
  if (threadIdx.x == 0) {
    float tt = sh[0] + sh[1] + sh[2] + sh[3];
    corr[p] = tt * (1.f / 147456.f);
  }
}

__global__ void bcast_out(const float* __restrict__ corr, float* __restrict__ out, int total) {
  int i = blockIdx.x * blockDim.x + threadIdx.x;
  if (i < total) out[i] = corr[i % 289];
}

// ============ host ============
extern "C" void kernel_launch(void* const* d_in, const int* in_sizes, int n_in,
                              void* d_out, int out_size, void* d_ws, size_t ws_size,
                              hipStream_t stream) {
  (void)in_sizes; (void)n_in; (void)ws_size; (void)out_size;
  const float* input1 = (const float*)d_in[0];
  const float* input2 = (const float*)d_in[1];
  const float* cw[5];
  const float* bg[5];
  const float* bb[5];
  for (int i = 0; i < 5; ++i) {
    cw[i] = (const float*)d_in[2 + 2 * i];
    bg[i] = (const float*)d_in[12 + 2 * i];
    bb[i] = (const float*)d_in[13 + 2 * i];
  }
  char* p = (char*)d_ws;
  auto alloc = [&](size_t bytes) {
    char* r = p;
    p += (bytes + 255) & ~(size_t)255;
    return r;
  };
  unsigned short* P = (unsigned short*)alloc(93000000);
  unsigned short* Q = (unsigned short*)alloc(7200000);
  unsigned short* R = (unsigned short*)alloc(23000000);
  float* O1 = (float*)alloc(32l * 22 * 22 * 128 * 4);
  float* O2 = (float*)alloc(32l * 6 * 6 * 128 * 4);
  unsigned short* W2 = (unsigned short*)alloc(25l * 256 * 96 * 2);
  unsigned short* W3 = (unsigned short*)alloc(9l * 256 * 256 * 2);
  unsigned short* W4 = (unsigned short*)alloc(9l * 256 * 192 * 2);
  unsigned short* W5 = (unsigned short*)alloc(9l * 128 * 192 * 2);
  float* part = (float*)alloc(128l * 256 * 2 * 4);
  float* sc = (float*)alloc(256 * 4);
  float* sh = (float*)alloc(256 * 4);
  float* corr = (float*)alloc(289 * 4);

  // weight transforms
  {
    long t2 = 25l * 256 * 96;
    wt_transform<<<(unsigned)((t2 + 255) / 256), 256, 0, stream>>>(cw[1], W2, 256, 256, 96, 25, t2);
    long t3 = 9l * 256 * 256;
    wt_transform<<<(unsigned)((t3 + 255) / 256), 256, 0, stream>>>(cw[2], W3, 192, 256, 256, 9, t3);
    long t4 = 9l * 256 * 192;
    wt_transform<<<(unsigned)((t4 + 255) / 256), 256, 0, stream>>>(cw[3], W4, 192, 256, 192, 9, t4);
    long t5 = 9l * 128 * 192;
    wt_transform<<<(unsigned)((t5 + 255) / 256), 256, 0, stream>>>(cw[4], W5, 128, 128, 192, 9, t5);
  }

  const int N = 32;
  auto stats_apply = [&](unsigned short* X, int C, long NP, const float* g, const float* b,
                         bool relu, float* outf) {
    int Cr = ((C + 63) / 64) * 64;
    bn_stats_part<<<128, Cr, 0, stream>>>(X, part, C, NP);
    bn_finalize<<<1, Cr, 0, stream>>>(part, g, b, sc, sh, C, 128, (float)NP);
    long t8 = NP * C / 8;
    unsigned blocks = (unsigned)((t8 + 255) / 256);
    if (outf)
      bn_apply_k<false, true><<<blocks, 256, 0, stream>>>(X, outf, sc, sh, C, t8);
    else
      bn_apply_k<true, false><<<blocks, 256, 0, stream>>>(X, X, sc, sh, C, t8);
  };
  auto mfma_conv = [&](int K, const unsigned short* in, const unsigned short* wt,
                       unsigned short* out, int Ci, int Hi, int Ho, int Co_pad, int Co_real) {
    int NPIX = N * Ho * Ho;
    dim3 g((unsigned)((NPIX + 127) / 128), (unsigned)(Co_pad / 128));
    if (K == 5)
      conv_mfma<5><<<g, 256, 0, stream>>>(in, wt, out, Ci, Hi, Hi, Ho, Ho, Co_pad, Co_real, NPIX);
    else
      conv_mfma<3><<<g, 256, 0, stream>>>(in, wt, out, Ci, Hi, Hi, Ho, Ho, Co_pad, Co_real, NPIX);
  };

  auto run_branch = [&](const float* input, int Hin, float* Oout) {
    int H1 = (Hin - 11) / 2 + 1;
    int P1 = (H1 - 3) / 2 + 1;
    int H2 = P1 - 4;
    int P2 = (H2 - 3) / 2 + 1;
    int H3 = P2 - 2, H4 = P2 - 4, H5 = P2 - 6;
    // conv1 -> P
    dim3 g1((unsigned)((H1 + 63) / 64), (unsigned)H1, (unsigned)(N * 3));
    conv1_k<<<g1, 256, 0, stream>>>(input, cw[0], P, Hin, Hin, H1, H1);
    stats_apply(P, 96, (long)N * H1 * H1, bg[0], bb[0], true, nullptr);
    // pool1 -> R
    long pt1 = (long)N * P1 * P1 * 96;
    pool_k<<<(unsigned)((pt1 + 255) / 256), 256, 0, stream>>>(P, R, 96, H1, H1, P1, P1, pt1);
    // conv2 -> P
    mfma_conv(5, R, W2, P, 96, P1, H2, 256, 256);
    stats_apply(P, 256, (long)N * H2 * H2, bg[1], bb[1], true, nullptr);
    // pool2 -> R
    long pt2 = (long)N * P2 * P2 * 256;
    pool_k<<<(unsigned)((pt2 + 255) / 256), 256, 0, stream>>>(P, R, 256, H2, H2, P2, P2, pt2);
    // conv3 -> P
    mfma_conv(3, R, W3, P, 256, P2, H3, 256, 192);
    stats_apply(P, 192, (long)N * H3 * H3, bg[2], bb[2], true, nullptr);
    // conv4 -> Q
    mfma_conv(3, P, W4, Q, 192, H3, H4, 256, 192);
    stats_apply(Q, 192, (long)N * H4 * H4, bg[3], bb[3], true, nullptr);
    // conv5 -> P
    mfma_conv(3, Q, W5, P, 192, H4, H5, 128, 128);
    stats_apply(P, 128, (long)N * H5 * H5, bg[4], bb[4], false, Oout);
  };

  run_branch(input1, 255, O1);
  run_branch(input2, 127, O2);

  xcorr_k<<<289, 256, 0, stream>>>(O1, O2, corr);
  bcast_out<<<(9248 + 255) / 256, 256, 0, stream>>>(corr, (float*)d_out, 9248);
}

// Round 4
// 2860.661 us; speedup vs baseline: 5.8602x; 1.2938x over previous
//
#include <hip/hip_runtime.h>
#include <hip/hip_bf16.h>
#include <cstdint>
#include <cstddef>

typedef __attribute__((ext_vector_type(8))) _Float16 f16x8;
typedef __attribute__((ext_vector_type(4))) float f32x4;

__device__ __forceinline__ float h2f(unsigned short u) {
  union { unsigned short s; _Float16 h; } x; x.s = u; return (float)x.h;
}
__device__ __forceinline__ unsigned short f2h(float f) {
  union { unsigned short s; _Float16 h; } x; x.h = (_Float16)f; return x.s;
}
__device__ __forceinline__ void gload_lds16(const void* g, void* l) {
  __builtin_amdgcn_global_load_lds((const __attribute__((address_space(1))) unsigned int*)g,
                                   (__attribute__((address_space(3))) unsigned int*)l, 16, 0, 0);
}

// ============ input transform: fp32 NCHW [N,3,H,W] -> fp16 [N,H,W,4] (c3=0) ============
__global__ void in_transform(const float* __restrict__ in, unsigned short* __restrict__ out,
                             int HW, int total) {
  int i = blockIdx.x * 256 + threadIdx.x;
  if (i >= total) return;
  int n = i / HW;
  int r = i - n * HW;
  const float* p = in + (long)n * 3 * HW + r;
  uint2 v;
  v.x = (unsigned)f2h(p[0]) | ((unsigned)f2h(p[HW]) << 16);
  v.y = (unsigned)f2h(p[2 * HW]);
  ((uint2*)out)[i] = v;
}

// ============ conv1 weight transform: [96][3][11][11] fp32 -> [17][128][32] fp16 ============
// K-index g = kk*32+j; run = g/8; ky = run/6; e = (run%6)*8 + (g&7); kx = e/4; c = e%4
__global__ void wt1_transform(const float* __restrict__ w, unsigned short* __restrict__ o,
                              int total) {
  int i = blockIdx.x * 256 + threadIdx.x;
  if (i >= total) return;
  int j = i & 31;
  int r = i >> 5;
  int co = r & 127;
  int kk = r >> 7;
  int run = kk * 4 + (j >> 3);
  int ky = run / 6;
  int e = (run - ky * 6) * 8 + (j & 7);
  int kx = e >> 2, c = e & 3;
  float v = 0.f;
  if (ky < 11 && kx < 11 && c < 3 && co < 96)
    v = w[((co * 3 + c) * 11 + ky) * 11 + kx];
  o[i] = f2h(v);
}

// ============ conv1 MFMA: fp16 [N,Hi,Wi,4] -> fp16 NHWC [N,Ho,Wo,96], K=11x11x3 s=2 ============
// 128 px x 128 co (96 real) tile, 17 K-chunks of 32, 4 waves
__global__ __launch_bounds__(256)
void conv1_mfma(const unsigned short* __restrict__ in, const unsigned short* __restrict__ wt,
                unsigned short* __restrict__ out, int Hi, int Wi, int Ho, int Wo, int NPIX) {
  __shared__ __align__(16) unsigned short sA[128 * 32];
  __shared__ __align__(16) unsigned short sB[128 * 32];
  __shared__ int sOB[128];
  const int t = threadIdx.x;
  const int px0 = blockIdx.x * 128;
  if (t < 128) {
    int g = px0 + t;
    int ob = -1;
    if (g < NPIX) {
      int n = g / (Ho * Wo);
      int r = g - n * Ho * Wo;
      int oy = r / Wo, ox = r - (r / Wo) * Wo;
      ob = ((n * Ho + oy) * Wo + ox) * 96;
    }
    sOB[t] = ob;
  }
  long rbase[2];
#pragma unroll
  for (int i = 0; i < 2; ++i) {
    int pxl = i * 64 + (t >> 2);
    int g = px0 + pxl;
    long rb = 0;
    if (g < NPIX) {
      int n = g / (Ho * Wo);
      int r = g - n * Ho * Wo;
      int oy = r / Wo, ox = r - (r / Wo) * Wo;
      rb = ((long)(n * Hi + 2 * oy) * Wi + 2 * ox) * 4;
    }
    rbase[i] = rb;
  }
  const int a4 = t & 3;
  f32x4 acc[4][4];
  f32x4 zz = {0.f, 0.f, 0.f, 0.f};
#pragma unroll
  for (int m = 0; m < 4; ++m)
#pragma unroll
    for (int n = 0; n < 4; ++n) acc[m][n] = zz;
  const int w = t >> 6;
  const int l = t & 63;
  const int wpx = (w & 1) * 64, wco = (w >> 1) * 64;
  const int arow = wpx + (l & 15);
  const int brow = wco + (l & 15);
  const int q8 = (l >> 4) * 8;
  const int W4 = Wi * 4;
  for (int kk = 0; kk < 17; ++kk) {
    int run = kk * 4 + a4;
    int ky = run / 6;
    int e0 = (run - ky * 6) * 8;
    long koff = (long)ky * W4 + e0;
    gload_lds16(in + rbase[0] + koff, &sA[t * 8]);
    gload_lds16(in + rbase[1] + koff, &sA[(256 + t) * 8]);
    const unsigned short* wp = wt + (long)kk * 4096;
    gload_lds16(wp + t * 8, &sB[t * 8]);
    gload_lds16(wp + 2048 + t * 8, &sB[(256 + t) * 8]);
    __syncthreads();
    f16x8 av[4], bv[4];
#pragma unroll
    for (int m = 0; m < 4; ++m) av[m] = *(const f16x8*)&sA[(arow + m * 16) * 32 + q8];
#pragma unroll
    for (int n = 0; n < 4; ++n) bv[n] = *(const f16x8*)&sB[(brow + n * 16) * 32 + q8];
#pragma unroll
    for (int m = 0; m < 4; ++m)
#pragma unroll
      for (int n = 0; n < 4; ++n)
        acc[m][n] = __builtin_amdgcn_mfma_f32_16x16x32_f16(av[m], bv[n], acc[m][n], 0, 0, 0);
    __syncthreads();
  }
#pragma unroll
  for (int m = 0; m < 4; ++m) {
#pragma unroll
    for (int r = 0; r < 4; ++r) {
      int pxl = wpx + m * 16 + (l >> 4) * 4 + r;
      int ob = sOB[pxl];
#pragma unroll
      for (int n = 0; n < 4; ++n) {
        int co = wco + n * 16 + (l & 15);
        if (ob >= 0 && co < 96) out[ob + co] = f2h(acc[m][n][r]);
      }
    }
  }
}

// ============ implicit-GEMM MFMA conv (stride 1, VALID), fp16 ============
template <int K>
__global__ __launch_bounds__(256)
void conv_mfma(const unsigned short* __restrict__ in, const unsigned short* __restrict__ wt,
               unsigned short* __restrict__ out,
               int Ci, int Hi, int Wi, int Ho, int Wo, int Co_pad, int Co_real, int NPIX) {
  __shared__ __align__(16) unsigned short sA[128 * 32];
  __shared__ __align__(16) unsigned short sB[128 * 32];
  __shared__ int sOB[128];
  const int t = threadIdx.x;
  const int px0 = blockIdx.x * 128;
  const int co0 = blockIdx.y * 128;
  if (t < 128) {
    int g = px0 + t;
    int ob = -1;
    if (g < NPIX) {
      int n = g / (Ho * Wo);
      int r = g - n * Ho * Wo;
      int oy = r / Wo, ox = r - (r / Wo) * Wo;
      ob = ((n * Ho + oy) * Wo + ox) * Co_real;
    }
    sOB[t] = ob;
  }
  long rbase[2];
#pragma unroll
  for (int i = 0; i < 2; ++i) {
    int pxl = i * 64 + (t >> 2);
    int g = px0 + pxl;
    long rb = 0;
    if (g < NPIX) {
      int n = g / (Ho * Wo);
      int r = g - n * Ho * Wo;
      int oy = r / Wo, ox = r - (r / Wo) * Wo;
      rb = ((long)(n * Hi + oy) * Wi + ox) * Ci;
    }
    rbase[i] = rb;
  }
  const int seg8 = (t & 3) * 8;
  const int colA = t >> 2;
  f32x4 acc[4][4];
  f32x4 zz = {0.f, 0.f, 0.f, 0.f};
#pragma unroll
  for (int m = 0; m < 4; ++m)
#pragma unroll
    for (int n = 0; n < 4; ++n) acc[m][n] = zz;
  const int w = t >> 6;
  const int l = t & 63;
  const int wpx = (w & 1) * 64, wco = (w >> 1) * 64;
  const int arow = wpx + (l & 15);
  const int brow = wco + (l & 15);
  const int q8 = (l >> 4) * 8;
  int ci0 = 0, kx = 0, ky = 0;
  const int NK = (Ci >> 5) * K * K;
  for (int kk = 0; kk < NK; ++kk) {
    long koff = (long)(ky * Wi + kx) * Ci + ci0 + seg8;
#pragma unroll
    for (int i = 0; i < 2; ++i)
      gload_lds16(in + rbase[i] + koff, &sA[(i * 256 + t) * 8]);
    long wbase = (long)((ky * K + kx) * Co_pad + co0) * Ci + ci0 + seg8;
#pragma unroll
    for (int i = 0; i < 2; ++i)
      gload_lds16(wt + wbase + (long)(i * 64 + colA) * Ci, &sB[(i * 256 + t) * 8]);
    __syncthreads();
    f16x8 av[4], bv[4];
#pragma unroll
    for (int m = 0; m < 4; ++m) av[m] = *(const f16x8*)&sA[(arow + m * 16) * 32 + q8];
#pragma unroll
    for (int n = 0; n < 4; ++n) bv[n] = *(const f16x8*)&sB[(brow + n * 16) * 32 + q8];
#pragma unroll
    for (int m = 0; m < 4; ++m)
#pragma unroll
      for (int n = 0; n < 4; ++n)
        acc[m][n] = __builtin_amdgcn_mfma_f32_16x16x32_f16(av[m], bv[n], acc[m][n], 0, 0, 0);
    __syncthreads();
    ci0 += 32;
    if (ci0 == Ci) { ci0 = 0; ++kx; if (kx == K) { kx = 0; ++ky; } }
  }
#pragma unroll
  for (int m = 0; m < 4; ++m) {
#pragma unroll
    for (int r = 0; r < 4; ++r) {
      int pxl = wpx + m * 16 + (l >> 4) * 4 + r;
      int ob = sOB[pxl];
#pragma unroll
      for (int n = 0; n < 4; ++n) {
        int co = co0 + wco + n * 16 + (l & 15);
        if (ob >= 0 && co < Co_real) out[ob + co] = f2h(acc[m][n][r]);
      }
    }
  }
}

// ============ weight transform: [Co][Ci][K][K] fp32 -> [K*K][Co_pad][Ci] fp16 ============
__global__ void wt_transform(const float* __restrict__ w, unsigned short* __restrict__ o,
                             int Co, int Co_pad, int Ci, int KK, long total) {
  long i = (long)blockIdx.x * blockDim.x + threadIdx.x;
  if (i >= total) return;
  int ci = (int)(i % Ci);
  long r = i / Ci;
  int co = (int)(r % Co_pad);
  int rk = (int)(r / Co_pad);
  float v = 0.f;
  if (co < Co) v = w[((long)co * Ci + ci) * KK + rk];
  o[i] = f2h(v);
}

// ============ BN stats (two-stage, deterministic) ============
__global__ void bn_stats_part(const unsigned short* __restrict__ x, float* __restrict__ part,
                              int C, long NP) {
  int c = threadIdx.x;
  if (c >= C) return;
  long per = (NP + gridDim.x - 1) / gridDim.x;
  long p0 = (long)blockIdx.x * per;
  long p1 = p0 + per;
  if (p1 > NP) p1 = NP;
  float s = 0.f, q = 0.f;
  for (long pp = p0; pp < p1; ++pp) {
    float v = h2f(x[pp * C + c]);
    s += v;
    q = fmaf(v, v, q);
  }
  part[((long)blockIdx.x * C + c) * 2] = s;
  part[((long)blockIdx.x * C + c) * 2 + 1] = q;
}

__global__ void bn_finalize(const float* __restrict__ part, const float* __restrict__ g,
                            const float* __restrict__ b, float* __restrict__ sc,
                            float* __restrict__ sh, int C, int nch, float cnt) {
  int c = threadIdx.x;
  if (c >= C) return;
  float s = 0.f, q = 0.f;
  for (int k = 0; k < nch; ++k) {
    s += part[((long)k * C + c) * 2];
    q += part[((long)k * C + c) * 2 + 1];
  }
  float m = s / cnt;
  float v = q / cnt - m * m;
  float r = rsqrtf(v + 1e-5f);
  float scl = r * g[c];
  sc[c] = scl;
  sh[c] = b[c] - m * scl;
}

// ============ BN apply (8-wide, in place or fp16->fp32) ============
template <bool RELU, bool OUTF32>
__global__ void bn_apply_k(const unsigned short* __restrict__ x, void* __restrict__ y,
                           const float* __restrict__ sc, const float* __restrict__ sh,
                           int C, long total8) {
  long i = (long)blockIdx.x * blockDim.x + threadIdx.x;
  if (i >= total8) return;
  const uint4 v = ((const uint4*)x)[i];
  long base = i * 8;
  int c0 = (int)(base % C);
  const float4 s0 = *(const float4*)&sc[c0];
  const float4 s1 = *(const float4*)&sc[c0 + 4];
  const float4 h0 = *(const float4*)&sh[c0];
  const float4 h1 = *(const float4*)&sh[c0 + 4];
  float f[8];
  f[0] = h2f((unsigned short)(v.x & 0xffff)); f[1] = h2f((unsigned short)(v.x >> 16));
  f[2] = h2f((unsigned short)(v.y & 0xffff)); f[3] = h2f((unsigned short)(v.y >> 16));
  f[4] = h2f((unsigned short)(v.z & 0xffff)); f[5] = h2f((unsigned short)(v.z >> 16));
  f[6] = h2f((unsigned short)(v.w & 0xffff)); f[7] = h2f((unsigned short)(v.w >> 16));
  const float S[8] = {s0.x, s0.y, s0.z, s0.w, s1.x, s1.y, s1.z, s1.w};
  const float H[8] = {h0.x, h0.y, h0.z, h0.w, h1.x, h1.y, h1.z, h1.w};
#pragma unroll
  for (int j = 0; j < 8; ++j) {
    f[j] = fmaf(f[j], S[j], H[j]);
    if (RELU) f[j] = fmaxf(f[j], 0.f);
  }
  if (OUTF32) {
    float4 o0 = {f[0], f[1], f[2], f[3]}, o1 = {f[4], f[5], f[6], f[7]};
    ((float4*)y)[2 * i] = o0;
    ((float4*)y)[2 * i + 1] = o1;
  } else {
    uint4 o;
    o.x = (unsigned)f2h(f[0]) | ((unsigned)f2h(f[1]) << 16);
    o.y = (unsigned)f2h(f[2]) | ((unsigned)f2h(f[3]) << 16);
    o.z = (unsigned)f2h(f[4]) | ((unsigned)f2h(f[5]) << 16);
    o.w = (unsigned)f2h(f[6]) | ((unsigned)f2h(f[7]) << 16);
    ((uint4*)y)[i] = o;
  }
}

// ============ MaxPool 3x3 s2 (NHWC fp16) ============
__global__ void pool_k(const unsigned short* __restrict__ in, unsigned short* __restrict__ out,
                       int C, int Hi, int Wi, int Ho, int Wo, long total) {
  long i = (long)blockIdx.x * blockDim.x + threadIdx.x;
  if (i >= total) return;
  int c = (int)(i % C);
  long r = i / C;
  int ox = (int)(r % Wo);
  r /= Wo;
  int oy = (int)(r % Ho);
  int n = (int)(r / Ho);
  const unsigned short* bp = in + ((long)(n * Hi + 2 * oy) * Wi + 2 * ox) * C + c;
  float m = -3.4e38f;
#pragma unroll
  for (int dy = 0; dy < 3; ++dy)
#pragma unroll
    for (int dx = 0; dx < 3; ++dx)
      m = fmaxf(m, h2f(bp[((long)dy * Wi + dx) * C]));
  out[i] = f2h(m);
}

// ============ cross-correlation (fp32, NHWC) ============
__global__ void xcorr_k(const float* __restrict__ o1, const float* __restrict__ o2,
                        float* __restrict__ corr) {
  const int p = blockIdx.x;
  const int oy = p / 17, ox = p - (p / 17) * 17;
  float acc = 0.f;
  for (int i = threadIdx.x; i < 147456; i += 256) {
    int c = i & 127;
    int r = i >> 7;
    int kx = r % 6;
    r /= 6;
    int ky = r % 6;
    int b = r / 6;
    acc = fmaf(o1[(((b * 22 + oy + ky) * 22) + ox + kx) * 128 + c], o2[i], acc);
  }
#pragma unroll
  for (int off = 32; off > 0; off >>= 1) acc += __shfl_down(acc, off, 64);
  __shared__ float sh[4];
  const int lane = threadIdx.x & 63, wid = threadIdx.x >> 6;
  if (lane == 0) sh[wid] = acc;
  __syncthreads();
  if (threadIdx.x == 0) {
    float tt = sh[0] + sh[1] + sh[2] + sh[3];
    corr[p] = tt * (1.f / 147456.f);
  }
}

__global__ void bcast_out(const float* __restrict__ corr, float* __restrict__ out, int total) {
  int i = blockIdx.x * blockDim.x + threadIdx.x;
  if (i < total) out[i] = corr[i % 289];
}

// ============ host ============
extern "C" void kernel_launch(void* const* d_in, const int* in_sizes, int n_in,
                              void* d_out, int out_size, void* d_ws, size_t ws_size,
                              hipStream_t stream) {
  (void)in_sizes; (void)n_in; (void)ws_size; (void)out_size;
  const float* input1 = (const float*)d_in[0];
  const float* input2 = (const float*)d_in[1];
  const float* cw[5];
  const float* bg[5];
  const float* bb[5];
  for (int i = 0; i < 5; ++i) {
    cw[i] = (const float*)d_in[2 + 2 * i];
    bg[i] = (const float*)d_in[12 + 2 * i];
    bb[i] = (const float*)d_in[13 + 2 * i];
  }
  char* p = (char*)d_ws;
  auto alloc = [&](size_t bytes) {
    char* r = p;
    p += (bytes + 255) & ~(size_t)255;
    return r;
  };
  unsigned short* P = (unsigned short*)alloc(93000000);
  unsigned short* Q = (unsigned short*)alloc(7200000);
  unsigned short* R = (unsigned short*)alloc(23000000);
  float* O1 = (float*)alloc(32l * 22 * 22 * 128 * 4);
  float* O2 = (float*)alloc(32l * 6 * 6 * 128 * 4);
  unsigned short* I1h = (unsigned short*)alloc(32l * 255 * 255 * 4 * 2 + 16384);
  unsigned short* I2h = (unsigned short*)alloc(32l * 127 * 127 * 4 * 2 + 16384);
  unsigned short* W1h = (unsigned short*)alloc(17l * 128 * 32 * 2);
  unsigned short* W2 = (unsigned short*)alloc(25l * 256 * 96 * 2);
  unsigned short* W3 = (unsigned short*)alloc(9l * 256 * 256 * 2);
  unsigned short* W4 = (unsigned short*)alloc(9l * 256 * 192 * 2);
  unsigned short* W5 = (unsigned short*)alloc(9l * 128 * 192 * 2);
  float* part = (float*)alloc(128l * 256 * 2 * 4);
  float* sc = (float*)alloc(256 * 4);
  float* sh = (float*)alloc(256 * 4);
  float* corr = (float*)alloc(289 * 4);

  // weight + input transforms
  {
    int t1 = 17 * 128 * 32;
    wt1_transform<<<(unsigned)((t1 + 255) / 256), 256, 0, stream>>>(cw[0], W1h, t1);
    long t2 = 25l * 256 * 96;
    wt_transform<<<(unsigned)((t2 + 255) / 256), 256, 0, stream>>>(cw[1], W2, 256, 256, 96, 25, t2);
    long t3 = 9l * 256 * 256;
    wt_transform<<<(unsigned)((t3 + 255) / 256), 256, 0, stream>>>(cw[2], W3, 192, 256, 256, 9, t3);
    long t4 = 9l * 256 * 192;
    wt_transform<<<(unsigned)((t4 + 255) / 256), 256, 0, stream>>>(cw[3], W4, 192, 256, 192, 9, t4);
    long t5 = 9l * 128 * 192;
    wt_transform<<<(unsigned)((t5 + 255) / 256), 256, 0, stream>>>(cw[4], W5, 128, 128, 192, 9, t5);
    int p1 = 32 * 255 * 255;
    in_transform<<<(unsigned)((p1 + 255) / 256), 256, 0, stream>>>(input1, I1h, 255 * 255, p1);
    int p2 = 32 * 127 * 127;
    in_transform<<<(unsigned)((p2 + 255) / 256), 256, 0, stream>>>(input2, I2h, 127 * 127, p2);
  }

  const int N = 32;
  auto stats_apply = [&](unsigned short* X, int C, long NP, const float* g, const float* b,
                         bool relu, float* outf) {
    int Cr = ((C + 63) / 64) * 64;
    bn_stats_part<<<128, Cr, 0, stream>>>(X, part, C, NP);
    bn_finalize<<<1, Cr, 0, stream>>>(part, g, b, sc, sh, C, 128, (float)NP);
    long t8 = NP * C / 8;
    unsigned blocks = (unsigned)((t8 + 255) / 256);
    if (outf)
      bn_apply_k<false, true><<<blocks, 256, 0, stream>>>(X, outf, sc, sh, C, t8);
    else
      bn_apply_k<true, false><<<blocks, 256, 0, stream>>>(X, X, sc, sh, C, t8);
  };
  auto mfma_conv = [&](int K, const unsigned short* in, const unsigned short* wt,
                       unsigned short* out, int Ci, int Hi, int Ho, int Co_pad, int Co_real) {
    int NPIX = N * Ho * Ho;
    dim3 g((unsigned)((NPIX + 127) / 128), (unsigned)(Co_pad / 128));
    if (K == 5)
      conv_mfma<5><<<g, 256, 0, stream>>>(in, wt, out, Ci, Hi, Hi, Ho, Ho, Co_pad, Co_real, NPIX);
    else
      conv_mfma<3><<<g, 256, 0, stream>>>(in, wt, out, Ci, Hi, Hi, Ho, Ho, Co_pad, Co_real, NPIX);
  };

  auto run_branch = [&](const unsigned short* inh, int Hin, float* Oout) {
    int H1 = (Hin - 11) / 2 + 1;
    int P1 = (H1 - 3) / 2 + 1;
    int H2 = P1 - 4;
    int P2 = (H2 - 3) / 2 + 1;
    int H3 = P2 - 2, H4 = P2 - 4, H5 = P2 - 6;
    // conv1 (MFMA) -> P
    int NPIX1 = N * H1 * H1;
    conv1_mfma<<<(unsigned)((NPIX1 + 127) / 128), 256, 0, stream>>>(
        inh, W1h, P, Hin, Hin, H1, H1, NPIX1);
    stats_apply(P, 96, (long)N * H1 * H1, bg[0], bb[0], true, nullptr);
    // pool1 -> R
    long pt1 = (long)N * P1 * P1 * 96;
    pool_k<<<(unsigned)((pt1 + 255) / 256), 256, 0, stream>>>(P, R, 96, H1, H1, P1, P1, pt1);
    // conv2 -> P
    mfma_conv(5, R, W2, P, 96, P1, H2, 256, 256);
    stats_apply(P, 256, (long)N * H2 * H2, bg[1], bb[1], true, nullptr);
    // pool2 -> R
    long pt2 = (long)N * P2 * P2 * 256;
    pool_k<<<(unsigned)((pt2 + 255) / 256), 256, 0, stream>>>(P, R, 256, H2, H2, P2, P2, pt2);
    // conv3 -> P
    mfma_conv(3, R, W3, P, 256, P2, H3, 256, 192);
    stats_apply(P, 192, (long)N * H3 * H3, bg[2], bb[2], true, nullptr);
    // conv4 -> Q
    mfma_conv(3, P, W4, Q, 192, H3, H4, 256, 192);
    stats_apply(Q, 192, (long)N * H4 * H4, bg[3], bb[3], true, nullptr);
    // conv5 -> P
    mfma_conv(3, Q, W5, P, 192, H4, H5, 128, 128);
    stats_apply(P, 128, (long)N * H5 * H5, bg[4], bb[4], false, Oout);
  };

  run_branch(I1h, 255, O1);
  run_branch(I2h, 127, O2);

  xcorr_k<<<289, 256, 0, stream>>>(O1, O2, corr);
  bcast_out<<<(9248 + 255) / 256, 256, 0, stream>>>(corr, (float*)d_out, 9248);
}